// Round 4
// baseline (598.340 us; speedup 1.0000x reference)
//
#include <hip/hip_runtime.h>

// ---------------- constants ----------------
#define HIDDEN 2048
#define NHEADS 16
#define NKV 4
#define HEAD_DIM 128
#define BB 2
#define TT 2048
#define MROWS (BB * TT)          // 4096
#define NQKV (NHEADS * HEAD_DIM + 2 * NKV * HEAD_DIM)  // 3072

typedef __attribute__((ext_vector_type(8))) short short8;
typedef __attribute__((ext_vector_type(4))) float f32x4;

__device__ __forceinline__ unsigned short f2bf(float f) {
    unsigned int u = __float_as_uint(f);
    unsigned int r = u + 0x7fffu + ((u >> 16) & 1u);
    return (unsigned short)(r >> 16);
}
__device__ __forceinline__ float b2f(unsigned short h) {
    return __uint_as_float(((unsigned int)h) << 16);
}

__device__ __forceinline__ void store_out(float* p, float v) { *p = v; }
__device__ __forceinline__ void store_out(unsigned short* p, float v) { *p = f2bf(v); }

// async global->LDS, 16B per lane; lds dest = wave-uniform base + lane*16
__device__ __forceinline__ void load_lds_16(const void* g, void* l) {
    __builtin_amdgcn_global_load_lds((const __attribute__((address_space(1))) unsigned int*)g,
                                     (__attribute__((address_space(3))) unsigned int*)l,
                                     16, 0, 0);
}

// ---------------- cast x to bf16 ----------------
__global__ void cast_x_kernel(const float* __restrict__ x, unsigned short* __restrict__ xb) {
    int i = blockIdx.x * 256 + threadIdx.x;
    float4 v = ((const float4*)x)[i];
    ushort4 o;
    o.x = f2bf(v.x); o.y = f2bf(v.y); o.z = f2bf(v.z); o.w = f2bf(v.w);
    ((ushort4*)xb)[i] = o;
}

// ---------------- pack wq|wk|wv -> WqkvT (N=3072 rows, K=2048 cols), bf16 ----------------
__global__ void pack_wqkvT_kernel(const float* __restrict__ wq, const float* __restrict__ wk,
                                  const float* __restrict__ wv, unsigned short* __restrict__ out) {
    __shared__ float tile[32][33];
    int n0 = blockIdx.x * 32, k0 = blockIdx.y * 32;
    int tx = threadIdx.x, ty = threadIdx.y;
#pragma unroll
    for (int i = 0; i < 32; i += 8) {
        int k = k0 + ty + i;
        int n = n0 + tx;
        float v;
        if (n < 2048)      v = wq[(size_t)k * 2048 + n];
        else if (n < 2560) v = wk[(size_t)k * 512 + (n - 2048)];
        else               v = wv[(size_t)k * 512 + (n - 2560)];
        tile[ty + i][tx] = v;
    }
    __syncthreads();
#pragma unroll
    for (int i = 0; i < 32; i += 8) {
        int n = n0 + ty + i;
        int k = k0 + tx;
        out[(size_t)n * HIDDEN + k] = f2bf(tile[tx][ty + i]);
    }
}

// ---------------- transpose wo -> WoT (N=2048 rows, K=2048 cols), bf16 ----------------
__global__ void pack_woT_kernel(const float* __restrict__ wo, unsigned short* __restrict__ out) {
    __shared__ float tile[32][33];
    int n0 = blockIdx.x * 32, k0 = blockIdx.y * 32;
    int tx = threadIdx.x, ty = threadIdx.y;
#pragma unroll
    for (int i = 0; i < 32; i += 8)
        tile[ty + i][tx] = wo[(size_t)(k0 + ty + i) * HIDDEN + n0 + tx];
    __syncthreads();
#pragma unroll
    for (int i = 0; i < 32; i += 8)
        out[(size_t)(n0 + ty + i) * HIDDEN + k0 + tx] = f2bf(tile[tx][ty + i]);
}

// ---------------- GEMM: C(MxN) = A(MxK bf16) @ Bt(NxK bf16)^T, m97-style staging ----------------
template <typename OutT>
__global__ __launch_bounds__(256) void gemm_bt_kernel(const unsigned short* __restrict__ A,
                                                      const unsigned short* __restrict__ Bt,
                                                      OutT* __restrict__ C,
                                                      int M, int N, int K) {
    __shared__ __align__(16) unsigned short sA[128 * 32];  // packed (global_load_lds order)
    __shared__ __align__(16) unsigned short sB[128 * 32];
    const int tid = threadIdx.x;
    const int lane = tid & 63, w = tid >> 6;
    const int quad = lane >> 4, l15 = lane & 15;
    const int wr = w >> 1, wc = w & 1;
    const int m0 = blockIdx.y * 128, n0 = blockIdx.x * 128;

    const unsigned short* gA = A + (size_t)(m0 + w * 16 + (lane >> 2)) * K + (lane & 3) * 8;
    const unsigned short* gB = Bt + (size_t)(n0 + w * 16 + (lane >> 2)) * K + (lane & 3) * 8;
    unsigned short* lA0 = &sA[(w * 16) * 32];
    unsigned short* lA1 = &sA[(64 + w * 16) * 32];
    unsigned short* lB0 = &sB[(w * 16) * 32];
    unsigned short* lB1 = &sB[(64 + w * 16) * 32];
    const size_t rstep = (size_t)64 * K;

    f32x4 acc[4][4];
    const f32x4 z4 = {0.f, 0.f, 0.f, 0.f};
#pragma unroll
    for (int mi = 0; mi < 4; ++mi)
#pragma unroll
        for (int ni = 0; ni < 4; ++ni) acc[mi][ni] = z4;

    for (int kk = 0; kk < K; kk += 32) {
        __syncthreads();
        load_lds_16(gA + kk, lA0);
        load_lds_16(gA + rstep + kk, lA1);
        load_lds_16(gB + kk, lB0);
        load_lds_16(gB + rstep + kk, lB1);
        __syncthreads();
        short8 af[4], bf[4];
#pragma unroll
        for (int i = 0; i < 4; ++i) {
            af[i] = *(const short8*)(&sA[(wr * 64 + i * 16 + l15) * 32 + quad * 8]);
            bf[i] = *(const short8*)(&sB[(wc * 64 + i * 16 + l15) * 32 + quad * 8]);
        }
#pragma unroll
        for (int mi = 0; mi < 4; ++mi)
#pragma unroll
            for (int ni = 0; ni < 4; ++ni)
                acc[mi][ni] = __builtin_amdgcn_mfma_f32_16x16x32_bf16(af[mi], bf[ni], acc[mi][ni], 0, 0, 0);
    }
#pragma unroll
    for (int mi = 0; mi < 4; ++mi)
#pragma unroll
        for (int ni = 0; ni < 4; ++ni)
#pragma unroll
            for (int r = 0; r < 4; ++r) {
                int gr = m0 + wr * 64 + mi * 16 + quad * 4 + r;
                int gc = n0 + wc * 64 + ni * 16 + l15;
                store_out(&C[(size_t)gr * N + gc], acc[mi][ni][r]);
            }
}

// ---------------- RoPE for Q,K ----------------
#define QP (MROWS * NHEADS * 64)  // 4194304
#define KP (MROWS * NKV * 64)     // 1048576
__global__ void rope_kernel(const unsigned short* __restrict__ qkv,
                            const float* __restrict__ cosb, const float* __restrict__ sinb,
                            unsigned short* __restrict__ Q, unsigned short* __restrict__ K) {
    int tid = blockIdx.x * 256 + threadIdx.x;
    if (tid < QP) {
        int d = tid & 63;
        int h = (tid >> 6) & 15;
        int row = tid >> 10;
        int t = row & (TT - 1), b = row >> 11;
        float x1 = b2f(qkv[(size_t)row * NQKV + h * 128 + d]);
        float x2 = b2f(qkv[(size_t)row * NQKV + h * 128 + d + 64]);
        float c = cosb[t * 64 + d], s = sinb[t * 64 + d];
        unsigned short* dst = Q + ((size_t)(b * NHEADS + h) * TT + t) * 128 + d;
        dst[0]  = f2bf(x1 * c - x2 * s);
        dst[64] = f2bf(x2 * c + x1 * s);
    } else {
        int p = tid - QP;
        int d = p & 63;
        int kh = (p >> 6) & 3;
        int row = p >> 8;
        int t = row & (TT - 1), b = row >> 11;
        float x1 = b2f(qkv[(size_t)row * NQKV + 2048 + kh * 128 + d]);
        float x2 = b2f(qkv[(size_t)row * NQKV + 2048 + kh * 128 + d + 64]);
        float c = cosb[t * 64 + d], s = sinb[t * 64 + d];
        unsigned short* dst = K + ((size_t)(b * NKV + kh) * TT + t) * 128 + d;
        dst[0]  = f2bf(x1 * c - x2 * s);
        dst[64] = f2bf(x2 * c + x1 * s);
    }
}

// ---------------- V transpose: qkv -> Vt[b][kvh][d][T] ----------------
__global__ void vtrans_kernel(const unsigned short* __restrict__ qkv,
                              unsigned short* __restrict__ Vt) {
    __shared__ unsigned short tile[32][33];
    int t0 = blockIdx.x * 32, d0 = blockIdx.y * 32, bz = blockIdx.z;  // bz = b*NKV+kh
    int b = bz >> 2, kh = bz & 3;
    int tx = threadIdx.x, ty = threadIdx.y;
#pragma unroll
    for (int i = 0; i < 32; i += 8)
        tile[ty + i][tx] = qkv[(size_t)(b * TT + t0 + ty + i) * NQKV + 2560 + kh * 128 + d0 + tx];
    __syncthreads();
#pragma unroll
    for (int i = 0; i < 32; i += 8)
        Vt[((size_t)bz * 128 + d0 + ty + i) * TT + t0 + tx] = tile[tx][ty + i];
}

// ---------------- flash attention: register-direct, no barriers ----------------
// One wave owns 32 q-rows; K/V fragments loaded straight from global (L2-resident);
// LDS used only for per-wave P transpose (C-layout -> A-layout) and O store transpose.
#define PS 68  // sP row stride
__global__ __launch_bounds__(256) void flash_kernel(const unsigned short* __restrict__ Qb,
                                                    const unsigned short* __restrict__ Kb,
                                                    const unsigned short* __restrict__ Vtb,
                                                    unsigned short* __restrict__ Ob) {
    __shared__ __align__(16) unsigned short sP[4][32 * PS];

    const int tid = threadIdx.x;
    const int w = tid >> 6, lane = tid & 63;
    const int quad = lane >> 4, l15 = lane & 15;
    const int b = blockIdx.z, h = blockIdx.y;
    const int qb = (int)gridDim.x - 1 - (int)blockIdx.x;  // big q-blocks first
    const int q0 = qb * 128;
    const int kvh = h >> 2;
    const unsigned short* Qh = Qb + (size_t)(b * NHEADS + h) * TT * 128;
    const unsigned short* Kh = Kb + (size_t)(b * NKV + kvh) * TT * 128;
    const unsigned short* Vth = Vtb + (size_t)(b * NKV + kvh) * 128 * TT;

    const int wrow0 = q0 + w * 32;

    // Q fragments: A[m=l15][k=quad*8+j], rows wrow0+mi*16+l15
    short8 aq[2][4];
#pragma unroll
    for (int mi = 0; mi < 2; ++mi)
#pragma unroll
        for (int dk = 0; dk < 4; ++dk)
            aq[mi][dk] = *(const short8*)(Qh + (size_t)(wrow0 + mi * 16 + l15) * 128 + dk * 32 + quad * 8);

    f32x4 accO[2][8], accL[2];
    const f32x4 z4 = {0.f, 0.f, 0.f, 0.f};
#pragma unroll
    for (int mi = 0; mi < 2; ++mi) {
        accL[mi] = z4;
#pragma unroll
        for (int nb = 0; nb < 8; ++nb) accO[mi][nb] = z4;
    }
    float m_i[2][4];
#pragma unroll
    for (int mi = 0; mi < 2; ++mi)
#pragma unroll
        for (int r = 0; r < 4; ++r) m_i[mi][r] = -1e30f;

    const short kone = (short)0x3F80;  // bf16 1.0
    const short8 ones = {kone, kone, kone, kone, kone, kone, kone, kone};
    const float scale = 0.08838834764831845f;  // 1/sqrt(128)
    unsigned short* sPw = &sP[w][0];

    for (int kv0 = 0; kv0 < wrow0 + 32; kv0 += 64) {  // per-wave bound: no wasted tiles
        // ---- S = Q K^T, K fragments direct from global ----
        f32x4 sacc[2][4];
#pragma unroll
        for (int mi = 0; mi < 2; ++mi)
#pragma unroll
            for (int nh = 0; nh < 4; ++nh) sacc[mi][nh] = z4;
#pragma unroll
        for (int nh = 0; nh < 4; ++nh) {
            short8 bk[4];
#pragma unroll
            for (int dk = 0; dk < 4; ++dk)
                bk[dk] = *(const short8*)(Kh + (size_t)(kv0 + nh * 16 + l15) * 128 + dk * 32 + quad * 8);
#pragma unroll
            for (int dk = 0; dk < 4; ++dk) {
                sacc[0][nh] = __builtin_amdgcn_mfma_f32_16x16x32_bf16(aq[0][dk], bk[dk], sacc[0][nh], 0, 0, 0);
                sacc[1][nh] = __builtin_amdgcn_mfma_f32_16x16x32_bf16(aq[1][dk], bk[dk], sacc[1][nh], 0, 0, 0);
            }
        }
        // ---- online softmax ----
#pragma unroll
        for (int mi = 0; mi < 2; ++mi) {
            const int fr0 = wrow0 + mi * 16;
            const bool needmask = (kv0 + 63) > fr0;
#pragma unroll
            for (int r = 0; r < 4; ++r) {
                int row = fr0 + quad * 4 + r;
                float sv[4];
                float mx = -1e30f;
#pragma unroll
                for (int nh = 0; nh < 4; ++nh) {
                    float s = sacc[mi][nh][r] * scale;
                    if (needmask) {
                        int col = kv0 + nh * 16 + l15;
                        s = (col <= row) ? s : -1e30f;
                    }
                    sv[nh] = s;
                    mx = fmaxf(mx, s);
                }
#pragma unroll
                for (int off = 1; off < 16; off <<= 1) mx = fmaxf(mx, __shfl_xor(mx, off, 64));
                float mold = m_i[mi][r];
                float mnew = fmaxf(mold, mx);
                m_i[mi][r] = mnew;
                float alpha = __expf(mold - mnew);
                accL[mi][r] *= alpha;
#pragma unroll
                for (int nb = 0; nb < 8; ++nb) accO[mi][nb][r] *= alpha;
#pragma unroll
                for (int nh = 0; nh < 4; ++nh)
                    sPw[(mi * 16 + quad * 4 + r) * PS + nh * 16 + l15] = f2bf(__expf(sv[nh] - mnew));
            }
        }
        __asm__ volatile("s_waitcnt lgkmcnt(0)" ::: "memory");
        // ---- P fragments (A-layout); l-sums via all-ones B ----
        short8 ap[2][2];
#pragma unroll
        for (int mi = 0; mi < 2; ++mi) {
#pragma unroll
            for (int kf = 0; kf < 2; ++kf)
                ap[mi][kf] = *(const short8*)(&sPw[(mi * 16 + l15) * PS + kf * 32 + quad * 8]);
            accL[mi] = __builtin_amdgcn_mfma_f32_16x16x32_bf16(ap[mi][0], ones, accL[mi], 0, 0, 0);
            accL[mi] = __builtin_amdgcn_mfma_f32_16x16x32_bf16(ap[mi][1], ones, accL[mi], 0, 0, 0);
        }
        // ---- O += P V, V fragments direct from global (Vt[d][T]) ----
#pragma unroll
        for (int nb = 0; nb < 8; ++nb) {
            short8 bv0 = *(const short8*)(Vth + (size_t)(nb * 16 + l15) * TT + kv0 + quad * 8);
            short8 bv1 = *(const short8*)(Vth + (size_t)(nb * 16 + l15) * TT + kv0 + 32 + quad * 8);
#pragma unroll
            for (int mi = 0; mi < 2; ++mi) {
                accO[mi][nb] = __builtin_amdgcn_mfma_f32_16x16x32_bf16(ap[mi][0], bv0, accO[mi][nb], 0, 0, 0);
                accO[mi][nb] = __builtin_amdgcn_mfma_f32_16x16x32_bf16(ap[mi][1], bv1, accO[mi][nb], 0, 0, 0);
            }
        }
    }

    // ---- epilogue: normalize, transpose via per-wave LDS, 16B/lane stores ----
    float inv[2][4];
#pragma unroll
    for (int mi = 0; mi < 2; ++mi)
#pragma unroll
        for (int r = 0; r < 4; ++r) inv[mi][r] = 1.0f / accL[mi][r];

    const size_t obase = ((size_t)b * TT + wrow0) * (NHEADS * HEAD_DIM) + h * 128;
#pragma unroll
    for (int half = 0; half < 2; ++half) {
        __asm__ volatile("s_waitcnt lgkmcnt(0)" ::: "memory");
#pragma unroll
        for (int mi = 0; mi < 2; ++mi)
#pragma unroll
            for (int nb2 = 0; nb2 < 4; ++nb2)
#pragma unroll
                for (int r = 0; r < 4; ++r)
                    sPw[(mi * 16 + quad * 4 + r) * PS + nb2 * 16 + l15] =
                        f2bf(accO[mi][half * 4 + nb2][r] * inv[mi][r]);
        __asm__ volatile("s_waitcnt lgkmcnt(0)" ::: "memory");
#pragma unroll
        for (int pass = 0; pass < 4; ++pass) {
            int row2 = pass * 8 + (lane >> 3);
            short8 vv = *(const short8*)(&sPw[row2 * PS + (lane & 7) * 8]);
            *(short8*)(Ob + obase + (size_t)row2 * (NHEADS * HEAD_DIM) + half * 64 + (lane & 7) * 8) = vv;
        }
    }
}

// ---------------- launch ----------------
extern "C" void kernel_launch(void* const* d_in, const int* in_sizes, int n_in,
                              void* d_out, int out_size, void* d_ws, size_t ws_size,
                              hipStream_t stream) {
    const float* x    = (const float*)d_in[0];
    const float* cosb = (const float*)d_in[1];
    const float* sinb = (const float*)d_in[2];
    const float* wq   = (const float*)d_in[3];
    const float* wk   = (const float*)d_in[4];
    const float* wv   = (const float*)d_in[5];
    const float* wo   = (const float*)d_in[6];
    float* out = (float*)d_out;

    char* ws = (char*)d_ws;
    unsigned short* xb    = (unsigned short*)(ws);                       // 16 MB
    unsigned short* wqkvT = (unsigned short*)(ws + (16u << 20));         // 12 MB
    unsigned short* woT   = (unsigned short*)(ws + (28u << 20));         // 8 MB
    unsigned short* qkv   = (unsigned short*)(ws + (36u << 20));         // 24 MB
    unsigned short* Qbuf  = (unsigned short*)(ws + (60u << 20));         // 16 MB
    unsigned short* Kbuf  = (unsigned short*)(ws + (76u << 20));         // 4 MB
    unsigned short* Vt    = (unsigned short*)(ws + (80u << 20));         // 4 MB
    unsigned short* attn  = (unsigned short*)(ws + (84u << 20));         // 16 MB -> 100 MB total

    cast_x_kernel<<<(MROWS * HIDDEN) / 4 / 256, 256, 0, stream>>>(x, xb);
    pack_wqkvT_kernel<<<dim3(NQKV / 32, HIDDEN / 32), dim3(32, 8), 0, stream>>>(wq, wk, wv, wqkvT);
    pack_woT_kernel<<<dim3(HIDDEN / 32, HIDDEN / 32), dim3(32, 8), 0, stream>>>(wo, woT);

    gemm_bt_kernel<unsigned short><<<dim3(NQKV / 128, MROWS / 128), 256, 0, stream>>>(
        xb, wqkvT, qkv, MROWS, NQKV, HIDDEN);

    rope_kernel<<<(QP + KP) / 256, 256, 0, stream>>>(qkv, cosb, sinb, Qbuf, Kbuf);
    vtrans_kernel<<<dim3(TT / 32, HEAD_DIM / 32, BB * NKV), dim3(32, 8), 0, stream>>>(qkv, Vt);

    flash_kernel<<<dim3(TT / 128, NHEADS, BB), 256, 0, stream>>>(Qbuf, Kbuf, Vt, attn);

    gemm_bt_kernel<float><<<dim3(HIDDEN / 128, MROWS / 128), 256, 0, stream>>>(
        attn, woT, out, MROWS, HIDDEN, HIDDEN);
}

// Round 5
// 388.429 us; speedup vs baseline: 1.5404x; 1.5404x over previous
//
#include <hip/hip_runtime.h>

// ---------------- constants ----------------
#define HIDDEN 2048
#define NHEADS 16
#define NKV 4
#define HEAD_DIM 128
#define BB 2
#define TT 2048
#define MROWS (BB * TT)          // 4096
#define NQKV (NHEADS * HEAD_DIM + 2 * NKV * HEAD_DIM)  // 3072

typedef __attribute__((ext_vector_type(8))) short short8;
typedef __attribute__((ext_vector_type(4))) float f32x4;

__device__ __forceinline__ unsigned short f2bf(float f) {
    unsigned int u = __float_as_uint(f);
    unsigned int r = u + 0x7fffu + ((u >> 16) & 1u);
    return (unsigned short)(r >> 16);
}
__device__ __forceinline__ float b2f(unsigned short h) {
    return __uint_as_float(((unsigned int)h) << 16);
}

__device__ __forceinline__ void store_out(float* p, float v) { *p = v; }
__device__ __forceinline__ void store_out(unsigned short* p, float v) { *p = f2bf(v); }

// async global->LDS, 16B per lane; lds dest = wave-uniform base + lane*16
__device__ __forceinline__ void load_lds_16(const void* g, void* l) {
    __builtin_amdgcn_global_load_lds((const __attribute__((address_space(1))) unsigned int*)g,
                                     (__attribute__((address_space(3))) unsigned int*)l,
                                     16, 0, 0);
}

// ---------------- cast x to bf16 ----------------
__global__ void cast_x_kernel(const float* __restrict__ x, unsigned short* __restrict__ xb) {
    int i = blockIdx.x * 256 + threadIdx.x;
    float4 v = ((const float4*)x)[i];
    ushort4 o;
    o.x = f2bf(v.x); o.y = f2bf(v.y); o.z = f2bf(v.z); o.w = f2bf(v.w);
    ((ushort4*)xb)[i] = o;
}

// ---------------- pack wq|wk|wv -> WqkvT (N=3072 rows, K=2048 cols), bf16 ----------------
__global__ void pack_wqkvT_kernel(const float* __restrict__ wq, const float* __restrict__ wk,
                                  const float* __restrict__ wv, unsigned short* __restrict__ out) {
    __shared__ float tile[32][33];
    int n0 = blockIdx.x * 32, k0 = blockIdx.y * 32;
    int tx = threadIdx.x, ty = threadIdx.y;
#pragma unroll
    for (int i = 0; i < 32; i += 8) {
        int k = k0 + ty + i;
        int n = n0 + tx;
        float v;
        if (n < 2048)      v = wq[(size_t)k * 2048 + n];
        else if (n < 2560) v = wk[(size_t)k * 512 + (n - 2048)];
        else               v = wv[(size_t)k * 512 + (n - 2560)];
        tile[ty + i][tx] = v;
    }
    __syncthreads();
#pragma unroll
    for (int i = 0; i < 32; i += 8) {
        int n = n0 + ty + i;
        int k = k0 + tx;
        out[(size_t)n * HIDDEN + k] = f2bf(tile[tx][ty + i]);
    }
}

// ---------------- transpose wo -> WoT (N=2048 rows, K=2048 cols), bf16 ----------------
__global__ void pack_woT_kernel(const float* __restrict__ wo, unsigned short* __restrict__ out) {
    __shared__ float tile[32][33];
    int n0 = blockIdx.x * 32, k0 = blockIdx.y * 32;
    int tx = threadIdx.x, ty = threadIdx.y;
#pragma unroll
    for (int i = 0; i < 32; i += 8)
        tile[ty + i][tx] = wo[(size_t)(k0 + ty + i) * HIDDEN + n0 + tx];
    __syncthreads();
#pragma unroll
    for (int i = 0; i < 32; i += 8)
        out[(size_t)(n0 + ty + i) * HIDDEN + k0 + tx] = f2bf(tile[tx][ty + i]);
}

// ---------------- GEMM: C(MxN) = A(MxK bf16) @ Bt(NxK bf16)^T, m97-style staging ----------------
template <typename OutT>
__global__ __launch_bounds__(256) void gemm_bt_kernel(const unsigned short* __restrict__ A,
                                                      const unsigned short* __restrict__ Bt,
                                                      OutT* __restrict__ C,
                                                      int M, int N, int K) {
    __shared__ __align__(16) unsigned short sA[128 * 32];
    __shared__ __align__(16) unsigned short sB[128 * 32];
    const int tid = threadIdx.x;
    const int lane = tid & 63, w = tid >> 6;
    const int quad = lane >> 4, l15 = lane & 15;
    const int wr = w >> 1, wc = w & 1;
    const int m0 = blockIdx.y * 128, n0 = blockIdx.x * 128;

    const unsigned short* gA = A + (size_t)(m0 + w * 16 + (lane >> 2)) * K + (lane & 3) * 8;
    const unsigned short* gB = Bt + (size_t)(n0 + w * 16 + (lane >> 2)) * K + (lane & 3) * 8;
    unsigned short* lA0 = &sA[(w * 16) * 32];
    unsigned short* lA1 = &sA[(64 + w * 16) * 32];
    unsigned short* lB0 = &sB[(w * 16) * 32];
    unsigned short* lB1 = &sB[(64 + w * 16) * 32];
    const size_t rstep = (size_t)64 * K;

    f32x4 acc[4][4];
    const f32x4 z4 = {0.f, 0.f, 0.f, 0.f};
#pragma unroll
    for (int mi = 0; mi < 4; ++mi)
#pragma unroll
        for (int ni = 0; ni < 4; ++ni) acc[mi][ni] = z4;

    for (int kk = 0; kk < K; kk += 32) {
        __syncthreads();
        load_lds_16(gA + kk, lA0);
        load_lds_16(gA + rstep + kk, lA1);
        load_lds_16(gB + kk, lB0);
        load_lds_16(gB + rstep + kk, lB1);
        __syncthreads();
        short8 af[4], bf[4];
#pragma unroll
        for (int i = 0; i < 4; ++i) {
            af[i] = *(const short8*)(&sA[(wr * 64 + i * 16 + l15) * 32 + quad * 8]);
            bf[i] = *(const short8*)(&sB[(wc * 64 + i * 16 + l15) * 32 + quad * 8]);
        }
#pragma unroll
        for (int mi = 0; mi < 4; ++mi)
#pragma unroll
            for (int ni = 0; ni < 4; ++ni)
                acc[mi][ni] = __builtin_amdgcn_mfma_f32_16x16x32_bf16(af[mi], bf[ni], acc[mi][ni], 0, 0, 0);
    }
#pragma unroll
    for (int mi = 0; mi < 4; ++mi)
#pragma unroll
        for (int ni = 0; ni < 4; ++ni)
#pragma unroll
            for (int r = 0; r < 4; ++r) {
                int gr = m0 + wr * 64 + mi * 16 + quad * 4 + r;
                int gc = n0 + wc * 64 + ni * 16 + l15;
                store_out(&C[(size_t)gr * N + gc], acc[mi][ni][r]);
            }
}

// ---------------- RoPE for Q,K ----------------
#define QP (MROWS * NHEADS * 64)  // 4194304
#define KP (MROWS * NKV * 64)     // 1048576
__global__ void rope_kernel(const unsigned short* __restrict__ qkv,
                            const float* __restrict__ cosb, const float* __restrict__ sinb,
                            unsigned short* __restrict__ Q, unsigned short* __restrict__ K) {
    int tid = blockIdx.x * 256 + threadIdx.x;
    if (tid < QP) {
        int d = tid & 63;
        int h = (tid >> 6) & 15;
        int row = tid >> 10;
        int t = row & (TT - 1), b = row >> 11;
        float x1 = b2f(qkv[(size_t)row * NQKV + h * 128 + d]);
        float x2 = b2f(qkv[(size_t)row * NQKV + h * 128 + d + 64]);
        float c = cosb[t * 64 + d], s = sinb[t * 64 + d];
        unsigned short* dst = Q + ((size_t)(b * NHEADS + h) * TT + t) * 128 + d;
        dst[0]  = f2bf(x1 * c - x2 * s);
        dst[64] = f2bf(x2 * c + x1 * s);
    } else {
        int p = tid - QP;
        int d = p & 63;
        int kh = (p >> 6) & 3;
        int row = p >> 8;
        int t = row & (TT - 1), b = row >> 11;
        float x1 = b2f(qkv[(size_t)row * NQKV + 2048 + kh * 128 + d]);
        float x2 = b2f(qkv[(size_t)row * NQKV + 2048 + kh * 128 + d + 64]);
        float c = cosb[t * 64 + d], s = sinb[t * 64 + d];
        unsigned short* dst = K + ((size_t)(b * NKV + kh) * TT + t) * 128 + d;
        dst[0]  = f2bf(x1 * c - x2 * s);
        dst[64] = f2bf(x2 * c + x1 * s);
    }
}

// ---------------- V transpose: qkv -> Vt[b][kvh][d][T] ----------------
__global__ void vtrans_kernel(const unsigned short* __restrict__ qkv,
                              unsigned short* __restrict__ Vt) {
    __shared__ unsigned short tile[32][33];
    int t0 = blockIdx.x * 32, d0 = blockIdx.y * 32, bz = blockIdx.z;  // bz = b*NKV+kh
    int b = bz >> 2, kh = bz & 3;
    int tx = threadIdx.x, ty = threadIdx.y;
#pragma unroll
    for (int i = 0; i < 32; i += 8)
        tile[ty + i][tx] = qkv[(size_t)(b * TT + t0 + ty + i) * NQKV + 2560 + kh * 128 + d0 + tx];
    __syncthreads();
#pragma unroll
    for (int i = 0; i < 32; i += 8)
        Vt[((size_t)bz * 128 + d0 + ty + i) * TT + t0 + tx] = tile[tx][ty + i];
}

// ---------------- flash attention: LDS-staged (global_load_lds), max-free softmax ----------------
// Block: 128 q-rows, 4 waves (32 rows each). KV tile = 64.
// sK[dk][kv][32]: QK B-frags read at stride 32 hw (2-way alias, free).
// sV[kf][d][32]:  PV B-frags same. Both packed for global_load_lds (lane*16B dest).
#define PS 68
__global__ __launch_bounds__(256) void flash_kernel(const unsigned short* __restrict__ Qb,
                                                    const unsigned short* __restrict__ Kb,
                                                    const unsigned short* __restrict__ Vtb,
                                                    unsigned short* __restrict__ Ob) {
    __shared__ __align__(16) unsigned short sK[4][64 * 32];   // 16 KB
    __shared__ __align__(16) unsigned short sV[2][128 * 32];  // 16 KB
    __shared__ __align__(16) unsigned short sP[4][32 * PS];   // 17.4 KB

    const int tid = threadIdx.x;
    const int w = tid >> 6, lane = tid & 63;
    const int quad = lane >> 4, l15 = lane & 15;
    const int b = blockIdx.z, h = blockIdx.y;
    const int qb = (int)gridDim.x - 1 - (int)blockIdx.x;  // big q-blocks first
    const int q0 = qb * 128;
    const int kvh = h >> 2;
    const unsigned short* Qh = Qb + (size_t)(b * NHEADS + h) * TT * 128;
    const unsigned short* Kh = Kb + (size_t)(b * NKV + kvh) * TT * 128;
    const unsigned short* Vth = Vtb + (size_t)(b * NKV + kvh) * 128 * TT;

    const int wrow0 = q0 + w * 32;

    // staging addresses (per-lane global; LDS dest wave-uniform + lane*16B)
    // K: wave w stages dk=w, kv-groups g=0..3: lane l -> row g*16+(l>>2), chunk (l&3)*8
    const unsigned short* gK = Kh + (size_t)(lane >> 2) * 128 + w * 32 + (lane & 3) * 8;
    // V: wave w stages kf=w>>1, d-groups g=(w&1)*4+j: lane l -> d-row g*16+(l>>2)
    const int vkf = w >> 1;
    const unsigned short* gV = Vth + (size_t)((w & 1) * 64 + (lane >> 2)) * TT + vkf * 32 + (lane & 3) * 8;

    // Q fragments: A[m=l15][k=quad*8+j], rows wrow0+mi*16+l15
    short8 aq[2][4];
#pragma unroll
    for (int mi = 0; mi < 2; ++mi)
#pragma unroll
        for (int dk = 0; dk < 4; ++dk)
            aq[mi][dk] = *(const short8*)(Qh + (size_t)(wrow0 + mi * 16 + l15) * 128 + dk * 32 + quad * 8);

    f32x4 accO[2][8], accL[2];
    const f32x4 z4 = {0.f, 0.f, 0.f, 0.f};
#pragma unroll
    for (int mi = 0; mi < 2; ++mi) {
        accL[mi] = z4;
#pragma unroll
        for (int nb = 0; nb < 8; ++nb) accO[mi][nb] = z4;
    }

    const short kone = (short)0x3F80;  // bf16 1.0
    const short8 ones = {kone, kone, kone, kone, kone, kone, kone, kone};
    const float scale = 0.08838834764831845f;  // 1/sqrt(128)
    unsigned short* sPw = &sP[w][0];

    for (int kv0 = 0; kv0 < q0 + 128; kv0 += 64) {
        __syncthreads();
        // ---- stage K tile (4 DMAs) and V tile (4 DMAs) per wave ----
#pragma unroll
        for (int g = 0; g < 4; ++g)
            load_lds_16(gK + (size_t)(kv0 + g * 16) * 128, &sK[w][g * 512]);
#pragma unroll
        for (int j = 0; j < 4; ++j)
            load_lds_16(gV + kv0 + (size_t)(j * 16) * TT, &sV[vkf][((w & 1) * 64 + j * 16) * 32]);
        __syncthreads();

        if (kv0 <= wrow0 + 31) {  // wave-uniform
            // ---- S = Q K^T ----
            f32x4 sacc[2][4];
#pragma unroll
            for (int mi = 0; mi < 2; ++mi)
#pragma unroll
                for (int nh = 0; nh < 4; ++nh) sacc[mi][nh] = z4;
#pragma unroll
            for (int nh = 0; nh < 4; ++nh) {
#pragma unroll
                for (int dk = 0; dk < 4; ++dk) {
                    short8 bk = *(const short8*)(&sK[dk][(nh * 16 + l15) * 32 + quad * 8]);
                    sacc[0][nh] = __builtin_amdgcn_mfma_f32_16x16x32_bf16(aq[0][dk], bk, sacc[0][nh], 0, 0, 0);
                    sacc[1][nh] = __builtin_amdgcn_mfma_f32_16x16x32_bf16(aq[1][dk], bk, sacc[1][nh], 0, 0, 0);
                }
            }
            // ---- max-free softmax: p = exp(s*scale), masked -> 0 ----
#pragma unroll
            for (int mi = 0; mi < 2; ++mi) {
                const int fr0 = wrow0 + mi * 16;
                const bool needmask = (kv0 + 63) > fr0;
#pragma unroll
                for (int r = 0; r < 4; ++r) {
                    int row = fr0 + quad * 4 + r;
#pragma unroll
                    for (int nh = 0; nh < 4; ++nh) {
                        float s = sacc[mi][nh][r] * scale;
                        if (needmask) {
                            int col = kv0 + nh * 16 + l15;
                            s = (col <= row) ? s : -1e30f;
                        }
                        sPw[(mi * 16 + quad * 4 + r) * PS + nh * 16 + l15] = f2bf(__expf(s));
                    }
                }
            }
            __asm__ volatile("s_waitcnt lgkmcnt(0)" ::: "memory");
            // ---- P frags (A-layout); row sums via ones-MFMA ----
            short8 ap[2][2];
#pragma unroll
            for (int mi = 0; mi < 2; ++mi) {
#pragma unroll
                for (int kf = 0; kf < 2; ++kf)
                    ap[mi][kf] = *(const short8*)(&sPw[(mi * 16 + l15) * PS + kf * 32 + quad * 8]);
                accL[mi] = __builtin_amdgcn_mfma_f32_16x16x32_bf16(ap[mi][0], ones, accL[mi], 0, 0, 0);
                accL[mi] = __builtin_amdgcn_mfma_f32_16x16x32_bf16(ap[mi][1], ones, accL[mi], 0, 0, 0);
            }
            // ---- O += P V ----
#pragma unroll
            for (int nb = 0; nb < 8; ++nb) {
                short8 bv0 = *(const short8*)(&sV[0][(nb * 16 + l15) * 32 + quad * 8]);
                short8 bv1 = *(const short8*)(&sV[1][(nb * 16 + l15) * 32 + quad * 8]);
#pragma unroll
                for (int mi = 0; mi < 2; ++mi) {
                    accO[mi][nb] = __builtin_amdgcn_mfma_f32_16x16x32_bf16(ap[mi][0], bv0, accO[mi][nb], 0, 0, 0);
                    accO[mi][nb] = __builtin_amdgcn_mfma_f32_16x16x32_bf16(ap[mi][1], bv1, accO[mi][nb], 0, 0, 0);
                }
            }
        }
    }

    // ---- epilogue: normalize, per-wave LDS transpose, 16B/lane stores ----
    float inv[2][4];
#pragma unroll
    for (int mi = 0; mi < 2; ++mi)
#pragma unroll
        for (int r = 0; r < 4; ++r) inv[mi][r] = 1.0f / accL[mi][r];

    const size_t obase = ((size_t)b * TT + wrow0) * (NHEADS * HEAD_DIM) + h * 128;
#pragma unroll
    for (int half = 0; half < 2; ++half) {
        __asm__ volatile("s_waitcnt lgkmcnt(0)" ::: "memory");
#pragma unroll
        for (int mi = 0; mi < 2; ++mi)
#pragma unroll
            for (int nb2 = 0; nb2 < 4; ++nb2)
#pragma unroll
                for (int r = 0; r < 4; ++r)
                    sPw[(mi * 16 + quad * 4 + r) * PS + nb2 * 16 + l15] =
                        f2bf(accO[mi][half * 4 + nb2][r] * inv[mi][r]);
        __asm__ volatile("s_waitcnt lgkmcnt(0)" ::: "memory");
#pragma unroll
        for (int pass = 0; pass < 4; ++pass) {
            int row2 = pass * 8 + (lane >> 3);
            short8 vv = *(const short8*)(&sPw[row2 * PS + (lane & 7) * 8]);
            *(short8*)(Ob + obase + (size_t)row2 * (NHEADS * HEAD_DIM) + half * 64 + (lane & 7) * 8) = vv;
        }
    }
}

// ---------------- launch ----------------
extern "C" void kernel_launch(void* const* d_in, const int* in_sizes, int n_in,
                              void* d_out, int out_size, void* d_ws, size_t ws_size,
                              hipStream_t stream) {
    const float* x    = (const float*)d_in[0];
    const float* cosb = (const float*)d_in[1];
    const float* sinb = (const float*)d_in[2];
    const float* wq   = (const float*)d_in[3];
    const float* wk   = (const float*)d_in[4];
    const float* wv   = (const float*)d_in[5];
    const float* wo   = (const float*)d_in[6];
    float* out = (float*)d_out;

    char* ws = (char*)d_ws;
    unsigned short* xb    = (unsigned short*)(ws);                       // 16 MB
    unsigned short* wqkvT = (unsigned short*)(ws + (16u << 20));         // 12 MB
    unsigned short* woT   = (unsigned short*)(ws + (28u << 20));         // 8 MB
    unsigned short* qkv   = (unsigned short*)(ws + (36u << 20));         // 24 MB
    unsigned short* Qbuf  = (unsigned short*)(ws + (60u << 20));         // 16 MB
    unsigned short* Kbuf  = (unsigned short*)(ws + (76u << 20));         // 4 MB
    unsigned short* Vt    = (unsigned short*)(ws + (80u << 20));         // 4 MB
    unsigned short* attn  = (unsigned short*)(ws + (84u << 20));         // 16 MB -> 100 MB total

    cast_x_kernel<<<(MROWS * HIDDEN) / 4 / 256, 256, 0, stream>>>(x, xb);
    pack_wqkvT_kernel<<<dim3(NQKV / 32, HIDDEN / 32), dim3(32, 8), 0, stream>>>(wq, wk, wv, wqkvT);
    pack_woT_kernel<<<dim3(HIDDEN / 32, HIDDEN / 32), dim3(32, 8), 0, stream>>>(wo, woT);

    gemm_bt_kernel<unsigned short><<<dim3(NQKV / 128, MROWS / 128), 256, 0, stream>>>(
        xb, wqkvT, qkv, MROWS, NQKV, HIDDEN);

    rope_kernel<<<(QP + KP) / 256, 256, 0, stream>>>(qkv, cosb, sinb, Qbuf, Kbuf);
    vtrans_kernel<<<dim3(TT / 32, HEAD_DIM / 32, BB * NKV), dim3(32, 8), 0, stream>>>(qkv, Vt);

    flash_kernel<<<dim3(TT / 128, NHEADS, BB), 256, 0, stream>>>(Qbuf, Kbuf, Vt, attn);

    gemm_bt_kernel<float><<<dim3(HIDDEN / 128, MROWS / 128), 256, 0, stream>>>(
        attn, woT, out, MROWS, HIDDEN, HIDDEN);
}

// Round 6
// 350.119 us; speedup vs baseline: 1.7090x; 1.1094x over previous
//
#include <hip/hip_runtime.h>

// ---------------- constants ----------------
#define HIDDEN 2048
#define NHEADS 16
#define NKV 4
#define HEAD_DIM 128
#define BB 2
#define TT 2048
#define MROWS (BB * TT)          // 4096
#define NQKV (NHEADS * HEAD_DIM + 2 * NKV * HEAD_DIM)  // 3072

typedef __attribute__((ext_vector_type(8))) short short8;
typedef __attribute__((ext_vector_type(4))) float f32x4;

#if __has_builtin(__builtin_amdgcn_exp2f)
#define EXP2F __builtin_amdgcn_exp2f
#else
#define EXP2F exp2f
#endif

__device__ __forceinline__ unsigned short f2bf(float f) {
    unsigned int u = __float_as_uint(f);
    unsigned int r = u + 0x7fffu + ((u >> 16) & 1u);
    return (unsigned short)(r >> 16);
}
__device__ __forceinline__ float b2f(unsigned short h) {
    return __uint_as_float(((unsigned int)h) << 16);
}

__device__ __forceinline__ void store_out(float* p, float v) { *p = v; }
__device__ __forceinline__ void store_out(unsigned short* p, float v) { *p = f2bf(v); }

// async global->LDS, 16B per lane; lds dest = wave-uniform base + lane*16
__device__ __forceinline__ void load_lds_16(const void* g, void* l) {
    __builtin_amdgcn_global_load_lds((const __attribute__((address_space(1))) unsigned int*)g,
                                     (__attribute__((address_space(3))) unsigned int*)l,
                                     16, 0, 0);
}

// ---------------- cast x to bf16 ----------------
__global__ void cast_x_kernel(const float* __restrict__ x, unsigned short* __restrict__ xb) {
    int i = blockIdx.x * 256 + threadIdx.x;
    float4 v = ((const float4*)x)[i];
    ushort4 o;
    o.x = f2bf(v.x); o.y = f2bf(v.y); o.z = f2bf(v.z); o.w = f2bf(v.w);
    ((ushort4*)xb)[i] = o;
}

// ---------------- pack wq|wk|wv -> WqkvT (N=3072 rows, K=2048 cols), bf16 ----------------
__global__ void pack_wqkvT_kernel(const float* __restrict__ wq, const float* __restrict__ wk,
                                  const float* __restrict__ wv, unsigned short* __restrict__ out) {
    __shared__ float tile[32][33];
    int n0 = blockIdx.x * 32, k0 = blockIdx.y * 32;
    int tx = threadIdx.x, ty = threadIdx.y;
#pragma unroll
    for (int i = 0; i < 32; i += 8) {
        int k = k0 + ty + i;
        int n = n0 + tx;
        float v;
        if (n < 2048)      v = wq[(size_t)k * 2048 + n];
        else if (n < 2560) v = wk[(size_t)k * 512 + (n - 2048)];
        else               v = wv[(size_t)k * 512 + (n - 2560)];
        tile[ty + i][tx] = v;
    }
    __syncthreads();
#pragma unroll
    for (int i = 0; i < 32; i += 8) {
        int n = n0 + ty + i;
        int k = k0 + tx;
        out[(size_t)n * HIDDEN + k] = f2bf(tile[tx][ty + i]);
    }
}

// ---------------- transpose wo -> WoT (N=2048 rows, K=2048 cols), bf16 ----------------
__global__ void pack_woT_kernel(const float* __restrict__ wo, unsigned short* __restrict__ out) {
    __shared__ float tile[32][33];
    int n0 = blockIdx.x * 32, k0 = blockIdx.y * 32;
    int tx = threadIdx.x, ty = threadIdx.y;
#pragma unroll
    for (int i = 0; i < 32; i += 8)
        tile[ty + i][tx] = wo[(size_t)(k0 + ty + i) * HIDDEN + n0 + tx];
    __syncthreads();
#pragma unroll
    for (int i = 0; i < 32; i += 8)
        out[(size_t)(n0 + ty + i) * HIDDEN + k0 + tx] = f2bf(tile[tx][ty + i]);
}

// ---------------- GEMM: C(MxN) = A(MxK bf16) @ Bt(NxK bf16)^T, m97-style staging ----------------
template <typename OutT>
__global__ __launch_bounds__(256) void gemm_bt_kernel(const unsigned short* __restrict__ A,
                                                      const unsigned short* __restrict__ Bt,
                                                      OutT* __restrict__ C,
                                                      int M, int N, int K) {
    __shared__ __align__(16) unsigned short sA[128 * 32];
    __shared__ __align__(16) unsigned short sB[128 * 32];
    const int tid = threadIdx.x;
    const int lane = tid & 63, w = tid >> 6;
    const int quad = lane >> 4, l15 = lane & 15;
    const int wr = w >> 1, wc = w & 1;
    const int m0 = blockIdx.y * 128, n0 = blockIdx.x * 128;

    const unsigned short* gA = A + (size_t)(m0 + w * 16 + (lane >> 2)) * K + (lane & 3) * 8;
    const unsigned short* gB = Bt + (size_t)(n0 + w * 16 + (lane >> 2)) * K + (lane & 3) * 8;
    unsigned short* lA0 = &sA[(w * 16) * 32];
    unsigned short* lA1 = &sA[(64 + w * 16) * 32];
    unsigned short* lB0 = &sB[(w * 16) * 32];
    unsigned short* lB1 = &sB[(64 + w * 16) * 32];
    const size_t rstep = (size_t)64 * K;

    f32x4 acc[4][4];
    const f32x4 z4 = {0.f, 0.f, 0.f, 0.f};
#pragma unroll
    for (int mi = 0; mi < 4; ++mi)
#pragma unroll
        for (int ni = 0; ni < 4; ++ni) acc[mi][ni] = z4;

    for (int kk = 0; kk < K; kk += 32) {
        __syncthreads();
        load_lds_16(gA + kk, lA0);
        load_lds_16(gA + rstep + kk, lA1);
        load_lds_16(gB + kk, lB0);
        load_lds_16(gB + rstep + kk, lB1);
        __syncthreads();
        short8 af[4], bf[4];
#pragma unroll
        for (int i = 0; i < 4; ++i) {
            af[i] = *(const short8*)(&sA[(wr * 64 + i * 16 + l15) * 32 + quad * 8]);
            bf[i] = *(const short8*)(&sB[(wc * 64 + i * 16 + l15) * 32 + quad * 8]);
        }
#pragma unroll
        for (int mi = 0; mi < 4; ++mi)
#pragma unroll
            for (int ni = 0; ni < 4; ++ni)
                acc[mi][ni] = __builtin_amdgcn_mfma_f32_16x16x32_bf16(af[mi], bf[ni], acc[mi][ni], 0, 0, 0);
    }
#pragma unroll
    for (int mi = 0; mi < 4; ++mi)
#pragma unroll
        for (int ni = 0; ni < 4; ++ni)
#pragma unroll
            for (int r = 0; r < 4; ++r) {
                int gr = m0 + wr * 64 + mi * 16 + quad * 4 + r;
                int gc = n0 + wc * 64 + ni * 16 + l15;
                store_out(&C[(size_t)gr * N + gc], acc[mi][ni][r]);
            }
}

// ---------------- RoPE for Q,K (Q pre-scaled by 1/sqrt(d) * log2(e)) ----------------
#define QP (MROWS * NHEADS * 64)  // 4194304
#define KP (MROWS * NKV * 64)     // 1048576
#define QSCL (0.08838834764831845f * 1.4426950408889634f)
__global__ void rope_kernel(const unsigned short* __restrict__ qkv,
                            const float* __restrict__ cosb, const float* __restrict__ sinb,
                            unsigned short* __restrict__ Q, unsigned short* __restrict__ K) {
    int tid = blockIdx.x * 256 + threadIdx.x;
    if (tid < QP) {
        int d = tid & 63;
        int h = (tid >> 6) & 15;
        int row = tid >> 10;
        int t = row & (TT - 1), b = row >> 11;
        float x1 = b2f(qkv[(size_t)row * NQKV + h * 128 + d]);
        float x2 = b2f(qkv[(size_t)row * NQKV + h * 128 + d + 64]);
        float c = cosb[t * 64 + d], s = sinb[t * 64 + d];
        unsigned short* dst = Q + ((size_t)(b * NHEADS + h) * TT + t) * 128 + d;
        dst[0]  = f2bf((x1 * c - x2 * s) * QSCL);
        dst[64] = f2bf((x2 * c + x1 * s) * QSCL);
    } else {
        int p = tid - QP;
        int d = p & 63;
        int kh = (p >> 6) & 3;
        int row = p >> 8;
        int t = row & (TT - 1), b = row >> 11;
        float x1 = b2f(qkv[(size_t)row * NQKV + 2048 + kh * 128 + d]);
        float x2 = b2f(qkv[(size_t)row * NQKV + 2048 + kh * 128 + d + 64]);
        float c = cosb[t * 64 + d], s = sinb[t * 64 + d];
        unsigned short* dst = K + ((size_t)(b * NKV + kh) * TT + t) * 128 + d;
        dst[0]  = f2bf(x1 * c - x2 * s);
        dst[64] = f2bf(x2 * c + x1 * s);
    }
}

// ---------------- V transpose: qkv -> Vt[b][kvh][d][T] ----------------
__global__ void vtrans_kernel(const unsigned short* __restrict__ qkv,
                              unsigned short* __restrict__ Vt) {
    __shared__ unsigned short tile[32][33];
    int t0 = blockIdx.x * 32, d0 = blockIdx.y * 32, bz = blockIdx.z;  // bz = b*NKV+kh
    int b = bz >> 2, kh = bz & 3;
    int tx = threadIdx.x, ty = threadIdx.y;
#pragma unroll
    for (int i = 0; i < 32; i += 8)
        tile[ty + i][tx] = qkv[(size_t)(b * TT + t0 + ty + i) * NQKV + 2560 + kh * 128 + d0 + tx];
    __syncthreads();
#pragma unroll
    for (int i = 0; i < 32; i += 8)
        Vt[((size_t)bz * 128 + d0 + ty + i) * TT + t0 + tx] = tile[tx][ty + i];
}

// ---------------- flash attention: LDS-staged, max-free softmax, balanced pairing ----------------
// Block: 128 q-rows, 4 waves (32 rows each). KV tile = 64.
// 1-D grid of 512: lin 0..255 -> qb 15..8 (big, launched first); lin 256..511 -> qb 0..7.
// Slot-paired blocks (lin, lin+256) share (h,b) and have qb summing to 15 -> 36 tiles/CU.
#define PS 68
__global__ __launch_bounds__(256) void flash_kernel(const unsigned short* __restrict__ Qb,
                                                    const unsigned short* __restrict__ Kb,
                                                    const unsigned short* __restrict__ Vtb,
                                                    unsigned short* __restrict__ Ob) {
    __shared__ __align__(16) unsigned short sK[4][64 * 32];   // 16 KB
    __shared__ __align__(16) unsigned short sV[2][128 * 32];  // 16 KB
    __shared__ __align__(16) unsigned short sP[4][32 * PS];   // 17.4 KB

    const int tid = threadIdx.x;
    const int w = tid >> 6, lane = tid & 63;
    const int quad = lane >> 4, l15 = lane & 15;

    const int lin = blockIdx.x;
    const int e = lin >> 8;           // 0: big half, 1: small half
    const int rem = lin & 255;
    const int h = rem & 15;
    const int b = (rem >> 4) & 1;
    const int j = rem >> 5;           // 0..7
    const int qb = e ? j : (15 - j);
    const int q0 = qb * 128;
    const int kvh = h >> 2;
    const unsigned short* Qh = Qb + (size_t)(b * NHEADS + h) * TT * 128;
    const unsigned short* Kh = Kb + (size_t)(b * NKV + kvh) * TT * 128;
    const unsigned short* Vth = Vtb + (size_t)(b * NKV + kvh) * 128 * TT;

    const int wrow0 = q0 + w * 32;

    // staging addresses (per-lane global; LDS dest wave-uniform + lane*16B)
    const unsigned short* gK = Kh + (size_t)(lane >> 2) * 128 + w * 32 + (lane & 3) * 8;
    const int vkf = w >> 1;
    const unsigned short* gV = Vth + (size_t)((w & 1) * 64 + (lane >> 2)) * TT + vkf * 32 + (lane & 3) * 8;

    // Q fragments: A[m=l15][k=quad*8+j], rows wrow0+mi*16+l15
    short8 aq[2][4];
#pragma unroll
    for (int mi = 0; mi < 2; ++mi)
#pragma unroll
        for (int dk = 0; dk < 4; ++dk)
            aq[mi][dk] = *(const short8*)(Qh + (size_t)(wrow0 + mi * 16 + l15) * 128 + dk * 32 + quad * 8);

    f32x4 accO[2][8], accL[2];
    const f32x4 z4 = {0.f, 0.f, 0.f, 0.f};
#pragma unroll
    for (int mi = 0; mi < 2; ++mi) {
        accL[mi] = z4;
#pragma unroll
        for (int nb = 0; nb < 8; ++nb) accO[mi][nb] = z4;
    }

    const short kone = (short)0x3F80;  // bf16 1.0
    const short8 ones = {kone, kone, kone, kone, kone, kone, kone, kone};
    unsigned short* sPw = &sP[w][0];

    for (int kv0 = 0; kv0 < q0 + 128; kv0 += 64) {
        __syncthreads();
#pragma unroll
        for (int g = 0; g < 4; ++g)
            load_lds_16(gK + (size_t)(kv0 + g * 16) * 128, &sK[w][g * 512]);
#pragma unroll
        for (int jj = 0; jj < 4; ++jj)
            load_lds_16(gV + kv0 + (size_t)(jj * 16) * TT, &sV[vkf][((w & 1) * 64 + jj * 16) * 32]);
        __syncthreads();

        if (kv0 <= wrow0 + 31) {  // wave-uniform
            // ---- S = Q K^T (Q pre-scaled so exp2 is direct) ----
            f32x4 sacc[2][4];
#pragma unroll
            for (int mi = 0; mi < 2; ++mi)
#pragma unroll
                for (int nh = 0; nh < 4; ++nh) sacc[mi][nh] = z4;
#pragma unroll
            for (int nh = 0; nh < 4; ++nh) {
#pragma unroll
                for (int dk = 0; dk < 4; ++dk) {
                    short8 bk = *(const short8*)(&sK[dk][(nh * 16 + l15) * 32 + quad * 8]);
                    sacc[0][nh] = __builtin_amdgcn_mfma_f32_16x16x32_bf16(aq[0][dk], bk, sacc[0][nh], 0, 0, 0);
                    sacc[1][nh] = __builtin_amdgcn_mfma_f32_16x16x32_bf16(aq[1][dk], bk, sacc[1][nh], 0, 0, 0);
                }
            }
            // ---- max-free softmax: p = exp2(s), masked -> 0 ----
#pragma unroll
            for (int mi = 0; mi < 2; ++mi) {
                const int fr0 = wrow0 + mi * 16;
                const bool needmask = (kv0 + 63) > fr0;
#pragma unroll
                for (int r = 0; r < 4; ++r) {
                    int row = fr0 + quad * 4 + r;
#pragma unroll
                    for (int nh = 0; nh < 4; ++nh) {
                        float s = sacc[mi][nh][r];
                        if (needmask) {
                            int col = kv0 + nh * 16 + l15;
                            s = (col <= row) ? s : -1e30f;
                        }
                        sPw[(mi * 16 + quad * 4 + r) * PS + nh * 16 + l15] = f2bf(EXP2F(s));
                    }
                }
            }
            __asm__ volatile("s_waitcnt lgkmcnt(0)" ::: "memory");
            // ---- P frags (A-layout); row sums via ones-MFMA ----
            short8 ap[2][2];
#pragma unroll
            for (int mi = 0; mi < 2; ++mi) {
#pragma unroll
                for (int kf = 0; kf < 2; ++kf)
                    ap[mi][kf] = *(const short8*)(&sPw[(mi * 16 + l15) * PS + kf * 32 + quad * 8]);
                accL[mi] = __builtin_amdgcn_mfma_f32_16x16x32_bf16(ap[mi][0], ones, accL[mi], 0, 0, 0);
                accL[mi] = __builtin_amdgcn_mfma_f32_16x16x32_bf16(ap[mi][1], ones, accL[mi], 0, 0, 0);
            }
            // ---- O += P V ----
#pragma unroll
            for (int nb = 0; nb < 8; ++nb) {
                short8 bv0 = *(const short8*)(&sV[0][(nb * 16 + l15) * 32 + quad * 8]);
                short8 bv1 = *(const short8*)(&sV[1][(nb * 16 + l15) * 32 + quad * 8]);
#pragma unroll
                for (int mi = 0; mi < 2; ++mi) {
                    accO[mi][nb] = __builtin_amdgcn_mfma_f32_16x16x32_bf16(ap[mi][0], bv0, accO[mi][nb], 0, 0, 0);
                    accO[mi][nb] = __builtin_amdgcn_mfma_f32_16x16x32_bf16(ap[mi][1], bv1, accO[mi][nb], 0, 0, 0);
                }
            }
        }
    }

    // ---- epilogue: normalize, per-wave LDS transpose, 16B/lane stores ----
    float inv[2][4];
#pragma unroll
    for (int mi = 0; mi < 2; ++mi)
#pragma unroll
        for (int r = 0; r < 4; ++r) inv[mi][r] = 1.0f / accL[mi][r];

    const size_t obase = ((size_t)b * TT + wrow0) * (NHEADS * HEAD_DIM) + h * 128;
#pragma unroll
    for (int half = 0; half < 2; ++half) {
        __asm__ volatile("s_waitcnt lgkmcnt(0)" ::: "memory");
#pragma unroll
        for (int mi = 0; mi < 2; ++mi)
#pragma unroll
            for (int nb2 = 0; nb2 < 4; ++nb2)
#pragma unroll
                for (int r = 0; r < 4; ++r)
                    sPw[(mi * 16 + quad * 4 + r) * PS + nb2 * 16 + l15] =
                        f2bf(accO[mi][half * 4 + nb2][r] * inv[mi][r]);
        __asm__ volatile("s_waitcnt lgkmcnt(0)" ::: "memory");
#pragma unroll
        for (int pass = 0; pass < 4; ++pass) {
            int row2 = pass * 8 + (lane >> 3);
            short8 vv = *(const short8*)(&sPw[row2 * PS + (lane & 7) * 8]);
            *(short8*)(Ob + obase + (size_t)row2 * (NHEADS * HEAD_DIM) + half * 64 + (lane & 7) * 8) = vv;
        }
    }
}

// ---------------- launch ----------------
extern "C" void kernel_launch(void* const* d_in, const int* in_sizes, int n_in,
                              void* d_out, int out_size, void* d_ws, size_t ws_size,
                              hipStream_t stream) {
    const float* x    = (const float*)d_in[0];
    const float* cosb = (const float*)d_in[1];
    const float* sinb = (const float*)d_in[2];
    const float* wq   = (const float*)d_in[3];
    const float* wk   = (const float*)d_in[4];
    const float* wv   = (const float*)d_in[5];
    const float* wo   = (const float*)d_in[6];
    float* out = (float*)d_out;

    char* ws = (char*)d_ws;
    unsigned short* xb    = (unsigned short*)(ws);                       // 16 MB
    unsigned short* wqkvT = (unsigned short*)(ws + (16u << 20));         // 12 MB
    unsigned short* woT   = (unsigned short*)(ws + (28u << 20));         // 8 MB
    unsigned short* qkv   = (unsigned short*)(ws + (36u << 20));         // 24 MB
    unsigned short* Qbuf  = (unsigned short*)(ws + (60u << 20));         // 16 MB
    unsigned short* Kbuf  = (unsigned short*)(ws + (76u << 20));         // 4 MB
    unsigned short* Vt    = (unsigned short*)(ws + (80u << 20));         // 4 MB
    unsigned short* attn  = (unsigned short*)(ws + (84u << 20));         // 16 MB -> 100 MB total

    cast_x_kernel<<<(MROWS * HIDDEN) / 4 / 256, 256, 0, stream>>>(x, xb);
    pack_wqkvT_kernel<<<dim3(NQKV / 32, HIDDEN / 32), dim3(32, 8), 0, stream>>>(wq, wk, wv, wqkvT);
    pack_woT_kernel<<<dim3(HIDDEN / 32, HIDDEN / 32), dim3(32, 8), 0, stream>>>(wo, woT);

    gemm_bt_kernel<unsigned short><<<dim3(NQKV / 128, MROWS / 128), 256, 0, stream>>>(
        xb, wqkvT, qkv, MROWS, NQKV, HIDDEN);

    rope_kernel<<<(QP + KP) / 256, 256, 0, stream>>>(qkv, cosb, sinb, Qbuf, Kbuf);
    vtrans_kernel<<<dim3(TT / 32, HEAD_DIM / 32, BB * NKV), dim3(32, 8), 0, stream>>>(qkv, Vt);

    flash_kernel<<<dim3(512), 256, 0, stream>>>(Qbuf, Kbuf, Vt, attn);

    gemm_bt_kernel<float><<<dim3(HIDDEN / 128, MROWS / 128), 256, 0, stream>>>(
        attn, woT, out, MROWS, HIDDEN, HIDDEN);
}

// Round 7
// 334.055 us; speedup vs baseline: 1.7911x; 1.0481x over previous
//
#include <hip/hip_runtime.h>

// ---------------- constants ----------------
#define HIDDEN 2048
#define NHEADS 16
#define NKV 4
#define HEAD_DIM 128
#define BB 2
#define TT 2048
#define MROWS (BB * TT)          // 4096
#define NQKV (NHEADS * HEAD_DIM + 2 * NKV * HEAD_DIM)  // 3072

typedef __attribute__((ext_vector_type(8))) short short8;
typedef __attribute__((ext_vector_type(4))) float f32x4;

#if __has_builtin(__builtin_amdgcn_exp2f)
#define EXP2F __builtin_amdgcn_exp2f
#else
#define EXP2F exp2f
#endif

__device__ __forceinline__ unsigned short f2bf(float f) {
    unsigned int u = __float_as_uint(f);
    unsigned int r = u + 0x7fffu + ((u >> 16) & 1u);
    return (unsigned short)(r >> 16);
}
__device__ __forceinline__ float b2f(unsigned short h) {
    return __uint_as_float(((unsigned int)h) << 16);
}

__device__ __forceinline__ void store_out(float* p, float v) { *p = v; }
__device__ __forceinline__ void store_out(unsigned short* p, float v) { *p = f2bf(v); }

// async global->LDS, 16B per lane; lds dest = wave-uniform base + lane*16
__device__ __forceinline__ void load_lds_16(const void* g, void* l) {
    __builtin_amdgcn_global_load_lds((const __attribute__((address_space(1))) unsigned int*)g,
                                     (__attribute__((address_space(3))) unsigned int*)l,
                                     16, 0, 0);
}

// ---------------- cast x to bf16 ----------------
__global__ void cast_x_kernel(const float* __restrict__ x, unsigned short* __restrict__ xb) {
    int i = blockIdx.x * 256 + threadIdx.x;
    float4 v = ((const float4*)x)[i];
    ushort4 o;
    o.x = f2bf(v.x); o.y = f2bf(v.y); o.z = f2bf(v.z); o.w = f2bf(v.w);
    ((ushort4*)xb)[i] = o;
}

// ---------------- pack wq|wk|wv -> WqkvT (N=3072 rows, K=2048 cols), bf16 ----------------
__global__ void pack_wqkvT_kernel(const float* __restrict__ wq, const float* __restrict__ wk,
                                  const float* __restrict__ wv, unsigned short* __restrict__ out) {
    __shared__ float tile[32][33];
    int n0 = blockIdx.x * 32, k0 = blockIdx.y * 32;
    int tx = threadIdx.x, ty = threadIdx.y;
#pragma unroll
    for (int i = 0; i < 32; i += 8) {
        int k = k0 + ty + i;
        int n = n0 + tx;
        float v;
        if (n < 2048)      v = wq[(size_t)k * 2048 + n];
        else if (n < 2560) v = wk[(size_t)k * 512 + (n - 2048)];
        else               v = wv[(size_t)k * 512 + (n - 2560)];
        tile[ty + i][tx] = v;
    }
    __syncthreads();
#pragma unroll
    for (int i = 0; i < 32; i += 8) {
        int n = n0 + ty + i;
        int k = k0 + tx;
        out[(size_t)n * HIDDEN + k] = f2bf(tile[tx][ty + i]);
    }
}

// ---------------- transpose wo -> WoT (N=2048 rows, K=2048 cols), bf16 ----------------
__global__ void pack_woT_kernel(const float* __restrict__ wo, unsigned short* __restrict__ out) {
    __shared__ float tile[32][33];
    int n0 = blockIdx.x * 32, k0 = blockIdx.y * 32;
    int tx = threadIdx.x, ty = threadIdx.y;
#pragma unroll
    for (int i = 0; i < 32; i += 8)
        tile[ty + i][tx] = wo[(size_t)(k0 + ty + i) * HIDDEN + n0 + tx];
    __syncthreads();
#pragma unroll
    for (int i = 0; i < 32; i += 8)
        out[(size_t)(n0 + ty + i) * HIDDEN + k0 + tx] = f2bf(tile[tx][ty + i]);
}

// ---------------- GEMM: C(MxN) = A(MxK bf16) @ Bt(NxK bf16)^T, m97-style staging ----------------
template <typename OutT>
__global__ __launch_bounds__(256) void gemm_bt_kernel(const unsigned short* __restrict__ A,
                                                      const unsigned short* __restrict__ Bt,
                                                      OutT* __restrict__ C,
                                                      int M, int N, int K) {
    __shared__ __align__(16) unsigned short sA[128 * 32];
    __shared__ __align__(16) unsigned short sB[128 * 32];
    const int tid = threadIdx.x;
    const int lane = tid & 63, w = tid >> 6;
    const int quad = lane >> 4, l15 = lane & 15;
    const int wr = w >> 1, wc = w & 1;
    const int m0 = blockIdx.y * 128, n0 = blockIdx.x * 128;

    const unsigned short* gA = A + (size_t)(m0 + w * 16 + (lane >> 2)) * K + (lane & 3) * 8;
    const unsigned short* gB = Bt + (size_t)(n0 + w * 16 + (lane >> 2)) * K + (lane & 3) * 8;
    unsigned short* lA0 = &sA[(w * 16) * 32];
    unsigned short* lA1 = &sA[(64 + w * 16) * 32];
    unsigned short* lB0 = &sB[(w * 16) * 32];
    unsigned short* lB1 = &sB[(64 + w * 16) * 32];
    const size_t rstep = (size_t)64 * K;

    f32x4 acc[4][4];
    const f32x4 z4 = {0.f, 0.f, 0.f, 0.f};
#pragma unroll
    for (int mi = 0; mi < 4; ++mi)
#pragma unroll
        for (int ni = 0; ni < 4; ++ni) acc[mi][ni] = z4;

    for (int kk = 0; kk < K; kk += 32) {
        __syncthreads();
        load_lds_16(gA + kk, lA0);
        load_lds_16(gA + rstep + kk, lA1);
        load_lds_16(gB + kk, lB0);
        load_lds_16(gB + rstep + kk, lB1);
        __syncthreads();
        short8 af[4], bf[4];
#pragma unroll
        for (int i = 0; i < 4; ++i) {
            af[i] = *(const short8*)(&sA[(wr * 64 + i * 16 + l15) * 32 + quad * 8]);
            bf[i] = *(const short8*)(&sB[(wc * 64 + i * 16 + l15) * 32 + quad * 8]);
        }
#pragma unroll
        for (int mi = 0; mi < 4; ++mi)
#pragma unroll
            for (int ni = 0; ni < 4; ++ni)
                acc[mi][ni] = __builtin_amdgcn_mfma_f32_16x16x32_bf16(af[mi], bf[ni], acc[mi][ni], 0, 0, 0);
    }
#pragma unroll
    for (int mi = 0; mi < 4; ++mi)
#pragma unroll
        for (int ni = 0; ni < 4; ++ni)
#pragma unroll
            for (int r = 0; r < 4; ++r) {
                int gr = m0 + wr * 64 + mi * 16 + quad * 4 + r;
                int gc = n0 + wc * 64 + ni * 16 + l15;
                store_out(&C[(size_t)gr * N + gc], acc[mi][ni][r]);
            }
}

// ---------------- RoPE for Q,K (Q pre-scaled by 1/sqrt(d) * log2(e)) ----------------
#define QP (MROWS * NHEADS * 64)  // 4194304
#define KP (MROWS * NKV * 64)     // 1048576
#define QSCL (0.08838834764831845f * 1.4426950408889634f)
__global__ void rope_kernel(const unsigned short* __restrict__ qkv,
                            const float* __restrict__ cosb, const float* __restrict__ sinb,
                            unsigned short* __restrict__ Q, unsigned short* __restrict__ K) {
    int tid = blockIdx.x * 256 + threadIdx.x;
    if (tid < QP) {
        int d = tid & 63;
        int h = (tid >> 6) & 15;
        int row = tid >> 10;
        int t = row & (TT - 1), b = row >> 11;
        float x1 = b2f(qkv[(size_t)row * NQKV + h * 128 + d]);
        float x2 = b2f(qkv[(size_t)row * NQKV + h * 128 + d + 64]);
        float c = cosb[t * 64 + d], s = sinb[t * 64 + d];
        unsigned short* dst = Q + ((size_t)(b * NHEADS + h) * TT + t) * 128 + d;
        dst[0]  = f2bf((x1 * c - x2 * s) * QSCL);
        dst[64] = f2bf((x2 * c + x1 * s) * QSCL);
    } else {
        int p = tid - QP;
        int d = p & 63;
        int kh = (p >> 6) & 3;
        int row = p >> 8;
        int t = row & (TT - 1), b = row >> 11;
        float x1 = b2f(qkv[(size_t)row * NQKV + 2048 + kh * 128 + d]);
        float x2 = b2f(qkv[(size_t)row * NQKV + 2048 + kh * 128 + d + 64]);
        float c = cosb[t * 64 + d], s = sinb[t * 64 + d];
        unsigned short* dst = K + ((size_t)(b * NKV + kh) * TT + t) * 128 + d;
        dst[0]  = f2bf(x1 * c - x2 * s);
        dst[64] = f2bf(x2 * c + x1 * s);
    }
}

// ---------------- V transpose: qkv -> Vt[b][kvh][d][T] ----------------
__global__ void vtrans_kernel(const unsigned short* __restrict__ qkv,
                              unsigned short* __restrict__ Vt) {
    __shared__ unsigned short tile[32][33];
    int t0 = blockIdx.x * 32, d0 = blockIdx.y * 32, bz = blockIdx.z;  // bz = b*NKV+kh
    int b = bz >> 2, kh = bz & 3;
    int tx = threadIdx.x, ty = threadIdx.y;
#pragma unroll
    for (int i = 0; i < 32; i += 8)
        tile[ty + i][tx] = qkv[(size_t)(b * TT + t0 + ty + i) * NQKV + 2560 + kh * 128 + d0 + tx];
    __syncthreads();
#pragma unroll
    for (int i = 0; i < 32; i += 8)
        Vt[((size_t)bz * 128 + d0 + ty + i) * TT + t0 + tx] = tile[tx][ty + i];
}

// ---------------- flash attention: S^T MFMA, KV-split + additive merge ----------------
// Grid 768 (1-D). member = lin>>8: 0,1 = two KV-halves of qb=15-j (partial, launched first);
// member 2 = qb=j full range (direct write). Trio (lin, lin+256, lin+512) lands on one CU:
// tiles (16-j) + (16-j) + (2j+2) = 34 per CU, max block 16 tiles.
// Max-free softmax => partials combine by simple addition in merge_kernel.
#define PS 68
__global__ __launch_bounds__(256, 3) void flash_kernel(const unsigned short* __restrict__ Qb,
                                                       const unsigned short* __restrict__ Kb,
                                                       const unsigned short* __restrict__ Vtb,
                                                       unsigned short* __restrict__ Ob,
                                                       unsigned short* __restrict__ Po,
                                                       float* __restrict__ Pl) {
    __shared__ __align__(16) unsigned short sK[4][64 * 32];   // 16 KB
    __shared__ __align__(16) unsigned short sV[2][128 * 32];  // 16 KB
    __shared__ __align__(16) unsigned short sP[4][32 * PS];   // 17.4 KB

    const int tid = threadIdx.x;
    const int w = tid >> 6, lane = tid & 63;
    const int quad = lane >> 4, l15 = lane & 15;

    const int lin = blockIdx.x;
    const int member = lin >> 8;      // 0,1: split halves (big qb); 2: small qb direct
    const int rem = lin & 255;
    const int h = rem & 15;
    const int b = (rem >> 4) & 1;
    const int j = rem >> 5;           // 0..7
    int qb, kvlo, kvhi;
    bool partial;
    if (member == 2) {
        qb = j; kvlo = 0; kvhi = (qb + 1) * 128; partial = false;
    } else {
        qb = 15 - j;
        int half = (qb + 1) * 64;
        kvlo = member ? half : 0;
        kvhi = member ? (qb + 1) * 128 : half;
        partial = true;
    }
    const int q0 = qb * 128;
    const int kvh = h >> 2;
    const unsigned short* Qh = Qb + (size_t)(b * NHEADS + h) * TT * 128;
    const unsigned short* Kh = Kb + (size_t)(b * NKV + kvh) * TT * 128;
    const unsigned short* Vth = Vtb + (size_t)(b * NKV + kvh) * 128 * TT;

    const int wrow0 = q0 + w * 32;

    // staging addresses (per-lane global; LDS dest wave-uniform + lane*16B)
    const unsigned short* gK = Kh + (size_t)(lane >> 2) * 128 + w * 32 + (lane & 3) * 8;
    const int vkf = w >> 1;
    const unsigned short* gV = Vth + (size_t)((w & 1) * 64 + (lane >> 2)) * TT + vkf * 32 + (lane & 3) * 8;

    // Q fragments (A-layout; also valid as B-operand): rows wrow0+h2*16+l15
    short8 aq[2][4];
#pragma unroll
    for (int mi = 0; mi < 2; ++mi)
#pragma unroll
        for (int dk = 0; dk < 4; ++dk)
            aq[mi][dk] = *(const short8*)(Qh + (size_t)(wrow0 + mi * 16 + l15) * 128 + dk * 32 + quad * 8);

    f32x4 accO[2][8], accL[2];
    const f32x4 z4 = {0.f, 0.f, 0.f, 0.f};
#pragma unroll
    for (int mi = 0; mi < 2; ++mi) {
        accL[mi] = z4;
#pragma unroll
        for (int nb = 0; nb < 8; ++nb) accO[mi][nb] = z4;
    }

    const short kone = (short)0x3F80;  // bf16 1.0
    const short8 ones = {kone, kone, kone, kone, kone, kone, kone, kone};
    unsigned short* sPw = &sP[w][0];

    for (int kv0 = kvlo; kv0 < kvhi; kv0 += 64) {
        __syncthreads();
#pragma unroll
        for (int g = 0; g < 4; ++g)
            load_lds_16(gK + (size_t)(kv0 + g * 16) * 128, &sK[w][g * 512]);
#pragma unroll
        for (int jj = 0; jj < 4; ++jj)
            load_lds_16(gV + kv0 + (size_t)(jj * 16) * TT, &sV[vkf][((w & 1) * 64 + jj * 16) * 32]);
        __syncthreads();

        if (kv0 <= wrow0 + 31) {  // wave-uniform
            // ---- S^T = K Q^T (operand-swapped): C-layout row=kv (quad*4+r), col=q (l15) ----
            f32x4 st[4][2];
#pragma unroll
            for (int t = 0; t < 4; ++t)
#pragma unroll
                for (int h2 = 0; h2 < 2; ++h2) st[t][h2] = z4;
#pragma unroll
            for (int t = 0; t < 4; ++t) {
#pragma unroll
                for (int dk = 0; dk < 4; ++dk) {
                    short8 ak = *(const short8*)(&sK[dk][(t * 16 + l15) * 32 + quad * 8]);
                    st[t][0] = __builtin_amdgcn_mfma_f32_16x16x32_bf16(ak, aq[0][dk], st[t][0], 0, 0, 0);
                    st[t][1] = __builtin_amdgcn_mfma_f32_16x16x32_bf16(ak, aq[1][dk], st[t][1], 0, 0, 0);
                }
            }
            // ---- max-free softmax; 4 consecutive kv per lane -> one b64 LDS write ----
#pragma unroll
            for (int h2 = 0; h2 < 2; ++h2) {
                const int rowbase = (h2 * 16 + l15) * PS;
                const int qg = wrow0 + h2 * 16 + l15;
#pragma unroll
                for (int t = 0; t < 4; ++t) {
                    const int kvb = kv0 + t * 16 + quad * 4;
                    const bool nm = (kv0 + t * 16 + 15) > (wrow0 + h2 * 16);
                    union { unsigned short u[4]; uint2 v; } pk;
#pragma unroll
                    for (int r = 0; r < 4; ++r) {
                        float p = EXP2F(st[t][h2][r]);
                        if (nm) p = (kvb + r <= qg) ? p : 0.f;
                        pk.u[r] = f2bf(p);
                    }
                    *(uint2*)(&sPw[rowbase + t * 16 + quad * 4]) = pk.v;
                }
            }
            __asm__ volatile("s_waitcnt lgkmcnt(0)" ::: "memory");
            // ---- P frags (A-layout); row sums via ones-MFMA ----
            short8 ap[2][2];
#pragma unroll
            for (int mi = 0; mi < 2; ++mi) {
#pragma unroll
                for (int kf = 0; kf < 2; ++kf)
                    ap[mi][kf] = *(const short8*)(&sPw[(mi * 16 + l15) * PS + kf * 32 + quad * 8]);
                accL[mi] = __builtin_amdgcn_mfma_f32_16x16x32_bf16(ap[mi][0], ones, accL[mi], 0, 0, 0);
                accL[mi] = __builtin_amdgcn_mfma_f32_16x16x32_bf16(ap[mi][1], ones, accL[mi], 0, 0, 0);
            }
            // ---- O += P V ----
#pragma unroll
            for (int nb = 0; nb < 8; ++nb) {
                short8 bv0 = *(const short8*)(&sV[0][(nb * 16 + l15) * 32 + quad * 8]);
                short8 bv1 = *(const short8*)(&sV[1][(nb * 16 + l15) * 32 + quad * 8]);
#pragma unroll
                for (int mi = 0; mi < 2; ++mi) {
                    accO[mi][nb] = __builtin_amdgcn_mfma_f32_16x16x32_bf16(ap[mi][0], bv0, accO[mi][nb], 0, 0, 0);
                    accO[mi][nb] = __builtin_amdgcn_mfma_f32_16x16x32_bf16(ap[mi][1], bv1, accO[mi][nb], 0, 0, 0);
                }
            }
        }
    }

    if (!partial) {
        // ---- direct: normalize, per-wave LDS transpose, 16B/lane stores ----
        float inv[2][4];
#pragma unroll
        for (int mi = 0; mi < 2; ++mi)
#pragma unroll
            for (int r = 0; r < 4; ++r) inv[mi][r] = 1.0f / accL[mi][r];

        const size_t obase = ((size_t)b * TT + wrow0) * (NHEADS * HEAD_DIM) + h * 128;
#pragma unroll
        for (int half = 0; half < 2; ++half) {
            __asm__ volatile("s_waitcnt lgkmcnt(0)" ::: "memory");
#pragma unroll
            for (int mi = 0; mi < 2; ++mi)
#pragma unroll
                for (int nb2 = 0; nb2 < 4; ++nb2)
#pragma unroll
                    for (int r = 0; r < 4; ++r)
                        sPw[(mi * 16 + quad * 4 + r) * PS + nb2 * 16 + l15] =
                            f2bf(accO[mi][half * 4 + nb2][r] * inv[mi][r]);
            __asm__ volatile("s_waitcnt lgkmcnt(0)" ::: "memory");
#pragma unroll
            for (int pass = 0; pass < 4; ++pass) {
                int row2 = pass * 8 + (lane >> 3);
                short8 vv = *(const short8*)(&sPw[row2 * PS + (lane & 7) * 8]);
                *(short8*)(Ob + obase + (size_t)row2 * (NHEADS * HEAD_DIM) + half * 64 + (lane & 7) * 8) = vv;
            }
        }
    } else {
        // ---- partial: raw accO (bf16) + accL (f32) to scratch ----
        const int part = member;
        const size_t pbase = ((size_t)(part * 2 + b) * 1024 + (wrow0 - 1024)) * 2048 + h * 128;
#pragma unroll
        for (int half = 0; half < 2; ++half) {
            __asm__ volatile("s_waitcnt lgkmcnt(0)" ::: "memory");
#pragma unroll
            for (int mi = 0; mi < 2; ++mi)
#pragma unroll
                for (int nb2 = 0; nb2 < 4; ++nb2)
#pragma unroll
                    for (int r = 0; r < 4; ++r)
                        sPw[(mi * 16 + quad * 4 + r) * PS + nb2 * 16 + l15] =
                            f2bf(accO[mi][half * 4 + nb2][r]);
            __asm__ volatile("s_waitcnt lgkmcnt(0)" ::: "memory");
#pragma unroll
            for (int pass = 0; pass < 4; ++pass) {
                int row2 = pass * 8 + (lane >> 3);
                short8 vv = *(const short8*)(&sPw[row2 * PS + (lane & 7) * 8]);
                *(short8*)(Po + pbase + (size_t)row2 * 2048 + half * 64 + (lane & 7) * 8) = vv;
            }
        }
        float* plb = Pl + ((size_t)(part * 2 + b) * 16 + h) * 1024 + (wrow0 - 1024);
        if (l15 == 0) {
#pragma unroll
            for (int mi = 0; mi < 2; ++mi)
#pragma unroll
                for (int r = 0; r < 4; ++r)
                    plb[mi * 16 + quad * 4 + r] = accL[mi][r];
        }
    }
}

// ---------------- merge: attn[rows 1024..2047] = (O0+O1)/(L0+L1) ----------------
__global__ void merge_kernel(const unsigned short* __restrict__ Po, const float* __restrict__ Pl,
                             unsigned short* __restrict__ attn) {
    int gid = blockIdx.x * 256 + threadIdx.x;
    size_t e8 = (size_t)gid * 8;
    int col = (int)(e8 & 2047);
    int rl  = (int)((e8 >> 11) & 1023);
    int b   = (int)(e8 >> 21);
    int h   = col >> 7;
    size_t i0 = ((size_t)b * 1024 + rl) * 2048 + col;            // part 0
    size_t i1 = ((size_t)(2 + b) * 1024 + rl) * 2048 + col;      // part 1
    float l = Pl[((size_t)b * 16 + h) * 1024 + rl] + Pl[((size_t)(2 + b) * 16 + h) * 1024 + rl];
    float inv = 1.0f / l;
    union { uint4 v; unsigned short u[8]; } a, c, o;
    a.v = *(const uint4*)(Po + i0);
    c.v = *(const uint4*)(Po + i1);
#pragma unroll
    for (int k = 0; k < 8; ++k)
        o.u[k] = f2bf((b2f(a.u[k]) + b2f(c.u[k])) * inv);
    *(uint4*)(attn + ((size_t)b * 2048 + 1024 + rl) * 2048 + col) = o.v;
}

// ---------------- launch ----------------
extern "C" void kernel_launch(void* const* d_in, const int* in_sizes, int n_in,
                              void* d_out, int out_size, void* d_ws, size_t ws_size,
                              hipStream_t stream) {
    const float* x    = (const float*)d_in[0];
    const float* cosb = (const float*)d_in[1];
    const float* sinb = (const float*)d_in[2];
    const float* wq   = (const float*)d_in[3];
    const float* wk   = (const float*)d_in[4];
    const float* wv   = (const float*)d_in[5];
    const float* wo   = (const float*)d_in[6];
    float* out = (float*)d_out;

    char* ws = (char*)d_ws;
    unsigned short* xb    = (unsigned short*)(ws);                       // 16 MB (dead after gemm1)
    unsigned short* wqkvT = (unsigned short*)(ws + (16u << 20));         // 12 MB (dead after gemm1)
    unsigned short* woT   = (unsigned short*)(ws + (28u << 20));         // 8 MB
    unsigned short* qkv   = (unsigned short*)(ws + (36u << 20));         // 24 MB
    unsigned short* Qbuf  = (unsigned short*)(ws + (60u << 20));         // 16 MB
    unsigned short* Kbuf  = (unsigned short*)(ws + (76u << 20));         // 4 MB
    unsigned short* Vt    = (unsigned short*)(ws + (80u << 20));         // 4 MB
    unsigned short* attn  = (unsigned short*)(ws + (84u << 20));         // 16 MB -> 100 MB total
    // overlays (regions dead by the time flash runs):
    unsigned short* Po    = (unsigned short*)(ws);                       // 16 MB partial O (over xb)
    float*          Pl    = (float*)(ws + (16u << 20));                  // 512 KB partial L (over wqkvT)

    cast_x_kernel<<<(MROWS * HIDDEN) / 4 / 256, 256, 0, stream>>>(x, xb);
    pack_wqkvT_kernel<<<dim3(NQKV / 32, HIDDEN / 32), dim3(32, 8), 0, stream>>>(wq, wk, wv, wqkvT);
    pack_woT_kernel<<<dim3(HIDDEN / 32, HIDDEN / 32), dim3(32, 8), 0, stream>>>(wo, woT);

    gemm_bt_kernel<unsigned short><<<dim3(NQKV / 128, MROWS / 128), 256, 0, stream>>>(
        xb, wqkvT, qkv, MROWS, NQKV, HIDDEN);

    rope_kernel<<<(QP + KP) / 256, 256, 0, stream>>>(qkv, cosb, sinb, Qbuf, Kbuf);
    vtrans_kernel<<<dim3(TT / 32, HEAD_DIM / 32, BB * NKV), dim3(32, 8), 0, stream>>>(qkv, Vt);

    flash_kernel<<<dim3(768), 256, 0, stream>>>(Qbuf, Kbuf, Vt, attn, Po, Pl);
    merge_kernel<<<dim3(2048), 256, 0, stream>>>(Po, Pl, attn);

    gemm_bt_kernel<float><<<dim3(HIDDEN / 128, MROWS / 128), 256, 0, stream>>>(
        attn, woT, out, MROWS, HIDDEN, HIDDEN);
}